// Round 16
// baseline (340.897 us; speedup 1.0000x reference)
//
#include <hip/hip_runtime.h>
#include <math.h>

// PolylineNet v16: R12's kernel (v10 tail-merge core at 1024 threads,
// 32 polylines/block) with NATURAL register allocation (1024,1).
// R12's 339us regression was solely __launch_bounds__(1024,4) forcing
// VGPR 128->64 + scratch spill (WRITE_SIZE 939MB). The core needs 128 VGPR
// naturally (v10 @512thr compiled to exactly 128) = 16 waves/CU budget.
// vs v13: MFMA x0.75, LDS weight-port traffic x0.5, same 16 waves/CU.

#define PP 20
#define HH 128
#define OO 256
#define PSTR 136       // k_head LDS stride

typedef __fp16   fp16x2 __attribute__((ext_vector_type(2)));
typedef _Float16 f16x4 __attribute__((ext_vector_type(4)));
typedef _Float16 f16x8 __attribute__((ext_vector_type(8)));
typedef float    f32x4 __attribute__((ext_vector_type(4)));

__device__ __forceinline__ f32x4 splat4(float x) { f32x4 v = {x, x, x, x}; return v; }

__device__ __forceinline__ f32x4 max4(f32x4 a, f32x4 b)
{
#if __has_builtin(__builtin_elementwise_max)
  return __builtin_elementwise_max(a, b);
#else
  f32x4 r;
  r[0] = fmaxf(a[0], b[0]); r[1] = fmaxf(a[1], b[1]);
  r[2] = fmaxf(a[2], b[2]); r[3] = fmaxf(a[3], b[3]);
  return r;
#endif
}

__device__ __forceinline__ f32x4 MFMA(f16x8 a, f16x8 b, f32x4 c)
{
  return __builtin_amdgcn_mfma_f32_16x16x32_f16(a, b, c, 0, 0, 0);
}

__device__ __forceinline__ f16x8 ldfrag2(const _Float16* p)
{
  f16x8 r;
  f16x4* r4 = reinterpret_cast<f16x4*>(&r);
  r4[0] = *reinterpret_cast<const f16x4*>(p);
  r4[1] = *reinterpret_cast<const f16x4*>(p + 16);
  return r;
}

__device__ __forceinline__ f16x8 pack8(const f32x4 a, const f32x4 b)
{
  union { fp16x2 h2[4]; f16x8 h8; } u;
  u.h2[0] = __builtin_amdgcn_cvt_pkrtz(a[0], a[1]);
  u.h2[1] = __builtin_amdgcn_cvt_pkrtz(a[2], a[3]);
  u.h2[2] = __builtin_amdgcn_cvt_pkrtz(b[0], b[1]);
  u.h2[3] = __builtin_amdgcn_cvt_pkrtz(b[2], b[3]);
  return u.h8;
}

// lane-select between two f16x8 (c true -> a), used for the tail tile's Pf.
__device__ __forceinline__ f16x8 sel8(bool c, const f16x8 a, const f16x8 b)
{
  union { f16x8 h; uint4 u; } ua, ub, ur;
  ua.h = a; ub.h = b;
  ur.u.x = c ? ua.u.x : ub.u.x;
  ur.u.y = c ? ua.u.y : ub.u.y;
  ur.u.z = c ? ua.u.z : ub.u.z;
  ur.u.w = c ? ua.u.w : ub.u.w;
  return ur.h;
}

// One K-step over all 8 N-tiles, 3 tiles: ONE weight ds_read feeds 3 MFMAs.
template<int KSROW>
__device__ __forceinline__ void gemm3(const _Float16* wbase, int ks,
                                      const f16x8 b0, const f16x8 b1, const f16x8 b2,
                                      f32x4 acc[8][3], int lane)
{
#pragma unroll
  for (int nt = 0; nt < 8; nt++) {
    const f16x8 wf = *(const f16x8*)(wbase + (size_t)(nt * KSROW + ks) * 512 + lane * 8);
    acc[nt][0] = MFMA(wf, b0, acc[nt][0]);
    acc[nt][1] = MFMA(wf, b1, acc[nt][1]);
    acc[nt][2] = MFMA(wf, b2, acc[nt][2]);
  }
}

__device__ __forceinline__ void zero_acc3(f32x4 acc[8][3])
{
#pragma unroll
  for (int nt = 0; nt < 8; nt++) {
    acc[nt][0] = splat4(0.f); acc[nt][1] = splat4(0.f); acc[nt][2] = splat4(0.f);
  }
}

// LayerNorm over channels for 3 tiles (per-lane stats; points live in l15).
template<bool DOMASKPOOL>
__device__ __forceinline__ void ln3(f32x4 acc[8][3],
                                    const float* __restrict__ bv,
                                    const float* __restrict__ gv,
                                    const float* __restrict__ bev,
                                    const f32x4 mfv[3],
                                    f32x4 pmA[8], f32x4 pmB[8],
                                    const f32x4 selA, const f32x4 selB, int lg)
{
  f32x4 sv[3], qv[3];
#pragma unroll
  for (int t = 0; t < 3; t++) { sv[t] = splat4(0.f); qv[t] = splat4(0.f); }
#pragma unroll
  for (int nt = 0; nt < 8; nt++) {
    const f32x4 bb = *(const f32x4*)(bv + 16 * nt + 4 * lg);
#pragma unroll
    for (int t = 0; t < 3; t++) {
      f32x4 v = acc[nt][t] + bb;
      acc[nt][t] = v;
      sv[t] += v;
      qv[t] = v * v + qv[t];
    }
  }
  float mu[3], rs[3];
#pragma unroll
  for (int t = 0; t < 3; t++) {
    float s = (sv[t][0] + sv[t][1]) + (sv[t][2] + sv[t][3]);
    float q = (qv[t][0] + qv[t][1]) + (qv[t][2] + qv[t][3]);
    s += __shfl_xor(s, 16, 64); s += __shfl_xor(s, 32, 64);
    q += __shfl_xor(q, 16, 64); q += __shfl_xor(q, 32, 64);
    mu[t] = s * (1.f / 128.f);
    rs[t] = rsqrtf(fmaxf(q * (1.f / 128.f) - mu[t] * mu[t], 0.f) + 1e-5f);
  }
  const f32x4 z4 = splat4(0.f);
  f32x4 rsv[3], nmv[3];
#pragma unroll
  for (int t = 0; t < 3; t++) { rsv[t] = splat4(rs[t]); nmv[t] = splat4(-mu[t] * rs[t]); }
#pragma unroll
  for (int nt = 0; nt < 8; nt++) {
    const f32x4 g4  = *(const f32x4*)(gv  + 16 * nt + 4 * lg);
    const f32x4 be4 = *(const f32x4*)(bev + 16 * nt + 4 * lg);
#pragma unroll
    for (int t = 0; t < 3; t++) {
      f32x4 tt = acc[nt][t] * rsv[t] + nmv[t];
      f32x4 v = max4(tt * g4 + be4, z4);
      if (DOMASKPOOL) {
        v = v * mfv[t];
        if (t == 0)      pmA[nt] = max4(pmA[nt], v);
        else if (t == 1) pmB[nt] = max4(pmB[nt], v);
        else { pmA[nt] = max4(pmA[nt], v * selA); pmB[nt] = max4(pmB[nt], v * selB); }
      }
      acc[nt][t] = v;
    }
  }
}

// ---- prep: L1-L4 fragment-linear (v7-verified) + FOW1/FOW2 [N][K] (R6-verified) ----
__global__ void prep_weights(const float* __restrict__ W1, const float* __restrict__ W2,
                             const float* __restrict__ F2W1, const float* __restrict__ F2W2,
                             const float* __restrict__ FO1, const float* __restrict__ FO2,
                             _Float16* __restrict__ wt)
{
  const int idx = blockIdx.x * 256 + threadIdx.x;
  if (idx >= 118784) return;
  float v;
  if (idx < 69632) {
    const int jj = idx & 7;
    const int lane = (idx >> 3) & 63;
    const int fg = idx >> 9;
    const int l15 = lane & 15, lg = lane >> 4;
    const int kin = 4 * lg + (jj & 3) + ((jj & 4) << 2);
    if (fg < 8)        { const int n = fg * 16 + l15;                  v = (kin < 13) ? W1[kin * 128 + n] : 0.f; }
    else if (fg < 40)  { const int f = fg - 8;   const int n = (f >> 2) * 16 + l15, k = (f & 3) * 32 + kin; v = W2[k * 128 + n]; }
    else if (fg < 104) { const int f = fg - 40;  const int n = (f >> 3) * 16 + l15, k = (f & 7) * 32 + kin; v = F2W1[k * 128 + n]; }
    else               { const int f = fg - 104; const int n = (f >> 2) * 16 + l15, k = (f & 3) * 32 + kin; v = F2W2[k * 128 + n]; }
  } else if (idx < 86016) { const int j = idx - 69632; const int n = j >> 7, k = j & 127; v = FO1[k * 128 + n]; }
  else                    { const int j = idx - 86016; const int n = j >> 7, k = j & 127; v = FO2[k * 256 + n]; }
  wt[idx] = (_Float16)v;
}

// ---- main kernel: 16 waves x 2 polylines, LDS weight pool, 1 barrier ----
extern "C" __global__ void __launch_bounds__(1024, 1)
polynet_main(const float* __restrict__ poly, const int* __restrict__ maskp,
             const float* __restrict__ b1,  const float* __restrict__ g1,  const float* __restrict__ be1,
             const float* __restrict__ b2,  const float* __restrict__ g2,  const float* __restrict__ be2,
             const float* __restrict__ f2b1, const float* __restrict__ f2g1, const float* __restrict__ f2be1,
             const float* __restrict__ f2b2, const float* __restrict__ f2g2, const float* __restrict__ f2be2,
             const _Float16* __restrict__ wt,
             _Float16* __restrict__ pooled2h, float* __restrict__ vldw)
{
  __shared__ _Float16 ldsw[69632];          // L1-L4 fragment pool (136 KB)
  __shared__ _Float16 ldsp[32][HH];         // pooled2 staging (8 KB)

  const int tid  = threadIdx.x;
  const int lane = tid & 63;
  const int w    = tid >> 6;                // 0..15
  const int l15  = lane & 15;
  const int lg   = lane >> 4;
  const int pidA = blockIdx.x * 32 + 2 * w;
  const int pidB = pidA + 1;

  // ---- stage weights (coalesced uint4 copy), one barrier ----
  {
    const uint4* src = (const uint4*)wt;
    uint4* dst = (uint4*)ldsw;
    for (int i = tid; i < 8704; i += 1024) dst[i] = src[i];
  }

  // ---- masks: lanes 0-19 load A's, lanes 32-51 load B's ----
  int mrow = 0;
  if (lane < PP)                 mrow = maskp[(size_t)pidA * PP + lane];
  else if (lane >= 32 && lane < 32 + PP) mrow = maskp[(size_t)pidB * PP + (lane - 32)];
  const float vldA = (__ballot(lane < PP && mrow != 0) != 0ULL) ? 1.f : 0.f;
  const float vldB = (__ballot(lane >= 32 && mrow != 0) != 0ULL) ? 1.f : 0.f;
  const int mi0 = __shfl(mrow, l15, 64);            // A mask[l15]
  const int mi1 = __shfl(mrow, 32 + l15, 64);       // B mask[l15]
  const int mi2 = __shfl(mrow, (l15 < 4) ? (16 + l15) : (44 + l15), 64); // tail
  f32x4 mfv[3];
  mfv[0] = splat4((mi0 != 0) ? 1.f : 0.f);
  mfv[1] = splat4((mi1 != 0) ? 1.f : 0.f);
  mfv[2] = splat4((l15 < 8 && mi2 != 0) ? 1.f : 0.f);
  const f32x4 selA = splat4((l15 < 4) ? 1.f : 0.f);
  const f32x4 selB = splat4((l15 >= 4 && l15 < 8) ? 1.f : 0.f);

  // ---- X -> B-frags for 3 tiles (K=32: 13 real, rest 0) ----
  const float* xp = poly + (size_t)pidA * (PP * 13);
  const float* xq = poly + (size_t)pidB * (PP * 13);
  f16x8 x0, x1, x2;
#pragma unroll
  for (int jj = 0; jj < 4; jj++) {
    const int k = 4 * lg + jj;
    float v0 = 0.f, v1 = 0.f, v2 = 0.f;
    if (k < 13) {
      v0 = xp[l15 * 13 + k];
      v1 = xq[l15 * 13 + k];
      if (l15 < 4)      v2 = xp[(16 + l15) * 13 + k];
      else if (l15 < 8) v2 = xq[(12 + l15) * 13 + k];
    }
    x0[jj] = (_Float16)v0;  x0[4 + jj] = (_Float16)0.f;
    x1[jj] = (_Float16)v1;  x1[4 + jj] = (_Float16)0.f;
    x2[jj] = (_Float16)v2;  x2[4 + jj] = (_Float16)0.f;
  }

  __syncthreads();   // weights staged

  const _Float16* wtL1 = ldsw;
  const _Float16* wtL2 = ldsw + 4096;
  const _Float16* wtL3 = ldsw + 20480;
  const _Float16* wtL4 = ldsw + 53248;

  f32x4 acc[8][3];
  f16x8 Hf0[4], Hf1[4], Hf2[4];
  f32x4 pmA[8], pmB[8];

  // ---- L1: K=32 ----
  zero_acc3(acc);
  gemm3<1>(wtL1, 0, x0, x1, x2, acc, lane);
  ln3<false>(acc, b1, g1, be1, mfv, pmA, pmB, selA, selB, lg);
#pragma unroll
  for (int ks = 0; ks < 4; ks++) {
    Hf0[ks] = pack8(acc[2 * ks][0], acc[2 * ks + 1][0]);
    Hf1[ks] = pack8(acc[2 * ks][1], acc[2 * ks + 1][1]);
    Hf2[ks] = pack8(acc[2 * ks][2], acc[2 * ks + 1][2]);
  }

  // ---- L2: K=128, mask+pool ----
  zero_acc3(acc);
#pragma unroll
  for (int ks = 0; ks < 4; ks++) gemm3<4>(wtL2, ks, Hf0[ks], Hf1[ks], Hf2[ks], acc, lane);
#pragma unroll
  for (int nt = 0; nt < 8; nt++) { pmA[nt] = splat4(0.f); pmB[nt] = splat4(0.f); }
  ln3<true>(acc, b2, g2, be2, mfv, pmA, pmB, selA, selB, lg);
#pragma unroll
  for (int nt = 0; nt < 8; nt++)
#pragma unroll
    for (int j = 0; j < 4; j++) {
      float p = pmA[nt][j];
      p = fmaxf(p, __shfl_xor(p, 1, 64));
      p = fmaxf(p, __shfl_xor(p, 2, 64));
      p = fmaxf(p, __shfl_xor(p, 4, 64));
      p = fmaxf(p, __shfl_xor(p, 8, 64));
      pmA[nt][j] = p;
      float q = pmB[nt][j];
      q = fmaxf(q, __shfl_xor(q, 1, 64));
      q = fmaxf(q, __shfl_xor(q, 2, 64));
      q = fmaxf(q, __shfl_xor(q, 4, 64));
      q = fmaxf(q, __shfl_xor(q, 8, 64));
      pmB[nt][j] = q;
    }
  f16x8 PfA[4], PfB[4], Pf2[4];
#pragma unroll
  for (int ks = 0; ks < 4; ks++) {
    PfA[ks] = pack8(pmA[2 * ks], pmA[2 * ks + 1]);
    PfB[ks] = pack8(pmB[2 * ks], pmB[2 * ks + 1]);
    Pf2[ks] = sel8(l15 < 4, PfA[ks], PfB[ks]);
  }
#pragma unroll
  for (int ks = 0; ks < 4; ks++) {
    Hf0[ks] = pack8(acc[2 * ks][0], acc[2 * ks + 1][0]);
    Hf1[ks] = pack8(acc[2 * ks][1], acc[2 * ks + 1][1]);
    Hf2[ks] = pack8(acc[2 * ks][2], acc[2 * ks + 1][2]);
  }

  // ---- L3: K=256 = feat (ks 0-3) + pooled (ks 4-7) ----
  zero_acc3(acc);
#pragma unroll
  for (int ks = 0; ks < 4; ks++) gemm3<8>(wtL3, ks, Hf0[ks], Hf1[ks], Hf2[ks], acc, lane);
#pragma unroll
  for (int ks = 4; ks < 8; ks++) gemm3<8>(wtL3, ks, PfA[ks - 4], PfB[ks - 4], Pf2[ks - 4], acc, lane);
  ln3<false>(acc, f2b1, f2g1, f2be1, mfv, pmA, pmB, selA, selB, lg);
#pragma unroll
  for (int ks = 0; ks < 4; ks++) {
    Hf0[ks] = pack8(acc[2 * ks][0], acc[2 * ks + 1][0]);
    Hf1[ks] = pack8(acc[2 * ks][1], acc[2 * ks + 1][1]);
    Hf2[ks] = pack8(acc[2 * ks][2], acc[2 * ks + 1][2]);
  }

  // ---- L4: K=128, mask+pool -> pooled2 ----
  zero_acc3(acc);
#pragma unroll
  for (int ks = 0; ks < 4; ks++) gemm3<4>(wtL4, ks, Hf0[ks], Hf1[ks], Hf2[ks], acc, lane);
#pragma unroll
  for (int nt = 0; nt < 8; nt++) { pmA[nt] = splat4(0.f); pmB[nt] = splat4(0.f); }
  ln3<true>(acc, f2b2, f2g2, f2be2, mfv, pmA, pmB, selA, selB, lg);
#pragma unroll
  for (int nt = 0; nt < 8; nt++)
#pragma unroll
    for (int j = 0; j < 4; j++) {
      float p = pmA[nt][j];
      p = fmaxf(p, __shfl_xor(p, 1, 64));
      p = fmaxf(p, __shfl_xor(p, 2, 64));
      p = fmaxf(p, __shfl_xor(p, 4, 64));
      p = fmaxf(p, __shfl_xor(p, 8, 64));
      pmA[nt][j] = p;
      float q = pmB[nt][j];
      q = fmaxf(q, __shfl_xor(q, 1, 64));
      q = fmaxf(q, __shfl_xor(q, 2, 64));
      q = fmaxf(q, __shfl_xor(q, 4, 64));
      q = fmaxf(q, __shfl_xor(q, 8, 64));
      pmB[nt][j] = q;
    }

  // ---- emit pooled2 (fp16) + vld; coalesced via per-wave LDS rows ----
  if (l15 == 0) {
#pragma unroll
    for (int nt = 0; nt < 8; nt++)
#pragma unroll
      for (int j = 0; j < 4; j++) {
        ldsp[2 * w][nt * 16 + 4 * lg + j]     = (_Float16)pmA[nt][j];
        ldsp[2 * w + 1][nt * 16 + 4 * lg + j] = (_Float16)pmB[nt][j];
      }
  }
  // same-wave LDS dependency (v7/v8/v9b/v10-verified pattern, no barrier)
  const unsigned int pvA = *(const unsigned int*)(&ldsp[2 * w][lane * 2]);
  const unsigned int pvB = *(const unsigned int*)(&ldsp[2 * w + 1][lane * 2]);
  *(unsigned int*)(pooled2h + (size_t)pidA * HH + lane * 2) = pvA;
  *(unsigned int*)(pooled2h + (size_t)pidB * HH + lane * 2) = pvB;
  if (lane == 0) { vldw[pidA] = vldA; vldw[pidB] = vldB; }
}

// ---- k_head (R6/R8/R10/R13-verified) ----
extern "C" __global__ void __launch_bounds__(256, 2)
k_head(const _Float16* __restrict__ pooled2h, const float* __restrict__ vldw,
       const _Float16* __restrict__ wt,
       const float* __restrict__ fob1, const float* __restrict__ fob2,
       float* __restrict__ out)
{
  __shared__ _Float16 Z1[64 * PSTR];
  const int tid = threadIdx.x, lane = tid & 63, w = tid >> 6;
  const int l15 = lane & 15, lg = lane >> 4;
  const int rbase = blockIdx.x * 64;

  const _Float16* FOW1t = wt + 69632;
  const _Float16* FOW2t = wt + 86016;

  {
    f32x4 az[4][2];
    const float bz0 = fob1[32 * w + l15];
    const float bz1 = fob1[32 * w + 16 + l15];
#pragma unroll
    for (int mt = 0; mt < 4; mt++) { az[mt][0] = splat4(bz0); az[mt][1] = splat4(bz1); }
    f16x8 bfr[2][4];
#pragma unroll
    for (int nt = 0; nt < 2; nt++) {
      const _Float16* bp = FOW1t + (size_t)((2 * w + nt) * 16 + l15) * 128 + 4 * lg;
#pragma unroll
      for (int ks = 0; ks < 4; ks++) bfr[nt][ks] = ldfrag2(bp + 32 * ks);
    }
#pragma unroll
    for (int mt = 0; mt < 4; mt++) {
      const _Float16* ap = pooled2h + (size_t)(rbase + mt * 16 + l15) * HH + 4 * lg;
#pragma unroll
      for (int ks = 0; ks < 4; ks++) {
        f16x8 a = ldfrag2(ap + 32 * ks);
        az[mt][0] = MFMA(a, bfr[0][ks], az[mt][0]);
        az[mt][1] = MFMA(a, bfr[1][ks], az[mt][1]);
      }
    }
#pragma unroll
    for (int mt = 0; mt < 4; mt++)
#pragma unroll
      for (int j = 0; j < 4; j++) {
        const int row = mt * 16 + lg * 4 + j;
        Z1[row * PSTR + 32 * w + l15]      = (_Float16)fmaxf(az[mt][0][j], 0.f);
        Z1[row * PSTR + 32 * w + 16 + l15] = (_Float16)fmaxf(az[mt][1][j], 0.f);
      }
  }
  __syncthreads();

  {
    f16x8 a[4][4];
#pragma unroll
    for (int mt = 0; mt < 4; mt++)
#pragma unroll
      for (int ks = 0; ks < 4; ks++)
        a[mt][ks] = ldfrag2(Z1 + (mt * 16 + l15) * PSTR + 4 * lg + 32 * ks);
    f32x4 o[4][4];
#pragma unroll
    for (int nt = 0; nt < 4; nt++) {
      const int c = (4 * w + nt) * 16 + l15;
      const float bo = fob2[c];
#pragma unroll
      for (int mt = 0; mt < 4; mt++) o[mt][nt] = splat4(bo);
      const _Float16* bp = FOW2t + (size_t)((4 * w + nt) * 16 + l15) * 128 + 4 * lg;
#pragma unroll
      for (int ks = 0; ks < 4; ks++) {
        f16x8 b = ldfrag2(bp + 32 * ks);
#pragma unroll
        for (int mt = 0; mt < 4; mt++) o[mt][nt] = MFMA(a[mt][ks], b, o[mt][nt]);
      }
    }
#pragma unroll
    for (int mt = 0; mt < 4; mt++)
#pragma unroll
      for (int j = 0; j < 4; j++) {
        const int row = mt * 16 + lg * 4 + j;
        const float v = vldw[rbase + row];
#pragma unroll
        for (int nt = 0; nt < 4; nt++)
          out[(size_t)(rbase + row) * OO + (4 * w + nt) * 16 + l15] = o[mt][nt][j] * v;
      }
  }
}

extern "C" void kernel_launch(void* const* d_in, const int* in_sizes, int n_in,
                              void* d_out, int out_size, void* d_ws, size_t ws_size,
                              hipStream_t stream)
{
  const float* poly  = (const float*)d_in[0];
  const int*   mask  = (const int*)d_in[1];
  const float* W1    = (const float*)d_in[2];
  const float* b1    = (const float*)d_in[3];
  const float* g1    = (const float*)d_in[4];
  const float* be1   = (const float*)d_in[5];
  const float* W2    = (const float*)d_in[6];
  const float* b2    = (const float*)d_in[7];
  const float* g2    = (const float*)d_in[8];
  const float* be2   = (const float*)d_in[9];
  const float* f2W1  = (const float*)d_in[10];
  const float* f2b1  = (const float*)d_in[11];
  const float* f2g1  = (const float*)d_in[12];
  const float* f2be1 = (const float*)d_in[13];
  const float* f2W2  = (const float*)d_in[14];
  const float* f2b2  = (const float*)d_in[15];
  const float* f2g2  = (const float*)d_in[16];
  const float* f2be2 = (const float*)d_in[17];
  const float* foW1  = (const float*)d_in[18];
  const float* fob1  = (const float*)d_in[19];
  const float* foW2  = (const float*)d_in[20];
  const float* fob2  = (const float*)d_in[21];
  float* out = (float*)d_out;

  const int npoly = in_sizes[0] / (PP * 13);   // 16384

  // ws layout: wt fp16 118784 halves (237,568 B) | pooled2h fp16 npoly*128 | vldw f32 npoly
  char* ws = (char*)d_ws;
  _Float16* wt       = (_Float16*)ws;
  _Float16* pooled2h = (_Float16*)(ws + 237568);
  float*    vldw     = (float*)(ws + 237568 + (size_t)npoly * HH * 2);

  prep_weights<<<dim3((118784 + 255) / 256), dim3(256), 0, stream>>>(
      W1, W2, f2W1, f2W2, foW1, foW2, wt);

  polynet_main<<<dim3(npoly / 32), dim3(1024), 0, stream>>>(
      poly, mask, b1, g1, be1, b2, g2, be2,
      f2b1, f2g1, f2be1, f2b2, f2g2, f2be2,
      wt, pooled2h, vldw);

  k_head<<<dim3(npoly / 64), dim3(256), 0, stream>>>(
      pooled2h, vldw, wt, fob1, fob2, out);
}

// Round 17
// 168.303 us; speedup vs baseline: 2.0255x; 2.0255x over previous
//
#include <hip/hip_runtime.h>
#include <math.h>

// PolylineNet v17: tail-merge core @512thr (R11-verified: 128 VGPR, no spill)
// + L3-only LDS pool (R15-verified-correct). 8 waves x 2 polylines = 16
// polys/block; LDS 68 KB -> 2 blocks/CU = 4 waves/SIMD at natural 128 VGPR
// (512 regs/SIMD exactly). L1/L2/L4 frags from global (L2); L3 (47% of
// fragment reads, 64 KB) from LDS. Core byte-identical to R11/R16.

#define PP 20
#define HH 128
#define OO 256
#define PSTR 136       // k_head LDS stride

typedef __fp16   fp16x2 __attribute__((ext_vector_type(2)));
typedef _Float16 f16x4 __attribute__((ext_vector_type(4)));
typedef _Float16 f16x8 __attribute__((ext_vector_type(8)));
typedef float    f32x4 __attribute__((ext_vector_type(4)));

__device__ __forceinline__ f32x4 splat4(float x) { f32x4 v = {x, x, x, x}; return v; }

__device__ __forceinline__ f32x4 max4(f32x4 a, f32x4 b)
{
#if __has_builtin(__builtin_elementwise_max)
  return __builtin_elementwise_max(a, b);
#else
  f32x4 r;
  r[0] = fmaxf(a[0], b[0]); r[1] = fmaxf(a[1], b[1]);
  r[2] = fmaxf(a[2], b[2]); r[3] = fmaxf(a[3], b[3]);
  return r;
#endif
}

__device__ __forceinline__ f32x4 MFMA(f16x8 a, f16x8 b, f32x4 c)
{
  return __builtin_amdgcn_mfma_f32_16x16x32_f16(a, b, c, 0, 0, 0);
}

__device__ __forceinline__ f16x8 ldfrag2(const _Float16* p)
{
  f16x8 r;
  f16x4* r4 = reinterpret_cast<f16x4*>(&r);
  r4[0] = *reinterpret_cast<const f16x4*>(p);
  r4[1] = *reinterpret_cast<const f16x4*>(p + 16);
  return r;
}

__device__ __forceinline__ f16x8 pack8(const f32x4 a, const f32x4 b)
{
  union { fp16x2 h2[4]; f16x8 h8; } u;
  u.h2[0] = __builtin_amdgcn_cvt_pkrtz(a[0], a[1]);
  u.h2[1] = __builtin_amdgcn_cvt_pkrtz(a[2], a[3]);
  u.h2[2] = __builtin_amdgcn_cvt_pkrtz(b[0], b[1]);
  u.h2[3] = __builtin_amdgcn_cvt_pkrtz(b[2], b[3]);
  return u.h8;
}

// lane-select between two f16x8 (c true -> a), used for the tail tile's Pf.
__device__ __forceinline__ f16x8 sel8(bool c, const f16x8 a, const f16x8 b)
{
  union { f16x8 h; uint4 u; } ua, ub, ur;
  ua.h = a; ub.h = b;
  ur.u.x = c ? ua.u.x : ub.u.x;
  ur.u.y = c ? ua.u.y : ub.u.y;
  ur.u.z = c ? ua.u.z : ub.u.z;
  ur.u.w = c ? ua.u.w : ub.u.w;
  return ur.h;
}

// One K-step over all 8 N-tiles, 3 tiles: ONE weight load feeds 3 MFMAs.
template<int KSROW>
__device__ __forceinline__ void gemm3(const _Float16* wbase, int ks,
                                      const f16x8 b0, const f16x8 b1, const f16x8 b2,
                                      f32x4 acc[8][3], int lane)
{
#pragma unroll
  for (int nt = 0; nt < 8; nt++) {
    const f16x8 wf = *(const f16x8*)(wbase + (size_t)(nt * KSROW + ks) * 512 + lane * 8);
    acc[nt][0] = MFMA(wf, b0, acc[nt][0]);
    acc[nt][1] = MFMA(wf, b1, acc[nt][1]);
    acc[nt][2] = MFMA(wf, b2, acc[nt][2]);
  }
}

__device__ __forceinline__ void zero_acc3(f32x4 acc[8][3])
{
#pragma unroll
  for (int nt = 0; nt < 8; nt++) {
    acc[nt][0] = splat4(0.f); acc[nt][1] = splat4(0.f); acc[nt][2] = splat4(0.f);
  }
}

// LayerNorm over channels for 3 tiles (per-lane stats; points live in l15).
template<bool DOMASKPOOL>
__device__ __forceinline__ void ln3(f32x4 acc[8][3],
                                    const float* __restrict__ bv,
                                    const float* __restrict__ gv,
                                    const float* __restrict__ bev,
                                    const f32x4 mfv[3],
                                    f32x4 pmA[8], f32x4 pmB[8],
                                    const f32x4 selA, const f32x4 selB, int lg)
{
  f32x4 sv[3], qv[3];
#pragma unroll
  for (int t = 0; t < 3; t++) { sv[t] = splat4(0.f); qv[t] = splat4(0.f); }
#pragma unroll
  for (int nt = 0; nt < 8; nt++) {
    const f32x4 bb = *(const f32x4*)(bv + 16 * nt + 4 * lg);
#pragma unroll
    for (int t = 0; t < 3; t++) {
      f32x4 v = acc[nt][t] + bb;
      acc[nt][t] = v;
      sv[t] += v;
      qv[t] = v * v + qv[t];
    }
  }
  float mu[3], rs[3];
#pragma unroll
  for (int t = 0; t < 3; t++) {
    float s = (sv[t][0] + sv[t][1]) + (sv[t][2] + sv[t][3]);
    float q = (qv[t][0] + qv[t][1]) + (qv[t][2] + qv[t][3]);
    s += __shfl_xor(s, 16, 64); s += __shfl_xor(s, 32, 64);
    q += __shfl_xor(q, 16, 64); q += __shfl_xor(q, 32, 64);
    mu[t] = s * (1.f / 128.f);
    rs[t] = rsqrtf(fmaxf(q * (1.f / 128.f) - mu[t] * mu[t], 0.f) + 1e-5f);
  }
  const f32x4 z4 = splat4(0.f);
  f32x4 rsv[3], nmv[3];
#pragma unroll
  for (int t = 0; t < 3; t++) { rsv[t] = splat4(rs[t]); nmv[t] = splat4(-mu[t] * rs[t]); }
#pragma unroll
  for (int nt = 0; nt < 8; nt++) {
    const f32x4 g4  = *(const f32x4*)(gv  + 16 * nt + 4 * lg);
    const f32x4 be4 = *(const f32x4*)(bev + 16 * nt + 4 * lg);
#pragma unroll
    for (int t = 0; t < 3; t++) {
      f32x4 tt = acc[nt][t] * rsv[t] + nmv[t];
      f32x4 v = max4(tt * g4 + be4, z4);
      if (DOMASKPOOL) {
        v = v * mfv[t];
        if (t == 0)      pmA[nt] = max4(pmA[nt], v);
        else if (t == 1) pmB[nt] = max4(pmB[nt], v);
        else { pmA[nt] = max4(pmA[nt], v * selA); pmB[nt] = max4(pmB[nt], v * selB); }
      }
      acc[nt][t] = v;
    }
  }
}

// ---- prep: L1-L4 fragment-linear (v7-verified) + FOW1/FOW2 [N][K] (R6-verified) ----
__global__ void prep_weights(const float* __restrict__ W1, const float* __restrict__ W2,
                             const float* __restrict__ F2W1, const float* __restrict__ F2W2,
                             const float* __restrict__ FO1, const float* __restrict__ FO2,
                             _Float16* __restrict__ wt)
{
  const int idx = blockIdx.x * 256 + threadIdx.x;
  if (idx >= 118784) return;
  float v;
  if (idx < 69632) {
    const int jj = idx & 7;
    const int lane = (idx >> 3) & 63;
    const int fg = idx >> 9;
    const int l15 = lane & 15, lg = lane >> 4;
    const int kin = 4 * lg + (jj & 3) + ((jj & 4) << 2);
    if (fg < 8)        { const int n = fg * 16 + l15;                  v = (kin < 13) ? W1[kin * 128 + n] : 0.f; }
    else if (fg < 40)  { const int f = fg - 8;   const int n = (f >> 2) * 16 + l15, k = (f & 3) * 32 + kin; v = W2[k * 128 + n]; }
    else if (fg < 104) { const int f = fg - 40;  const int n = (f >> 3) * 16 + l15, k = (f & 7) * 32 + kin; v = F2W1[k * 128 + n]; }
    else               { const int f = fg - 104; const int n = (f >> 2) * 16 + l15, k = (f & 3) * 32 + kin; v = F2W2[k * 128 + n]; }
  } else if (idx < 86016) { const int j = idx - 69632; const int n = j >> 7, k = j & 127; v = FO1[k * 128 + n]; }
  else                    { const int j = idx - 86016; const int n = j >> 7, k = j & 127; v = FO2[k * 256 + n]; }
  wt[idx] = (_Float16)v;
}

// ---- main kernel: 8 waves x 2 polylines, L3-only LDS pool (68 KB) ----
extern "C" __global__ void __launch_bounds__(512, 2)
polynet_main(const float* __restrict__ poly, const int* __restrict__ maskp,
             const float* __restrict__ b1,  const float* __restrict__ g1,  const float* __restrict__ be1,
             const float* __restrict__ b2,  const float* __restrict__ g2,  const float* __restrict__ be2,
             const float* __restrict__ f2b1, const float* __restrict__ f2g1, const float* __restrict__ f2be1,
             const float* __restrict__ f2b2, const float* __restrict__ f2g2, const float* __restrict__ f2be2,
             const _Float16* __restrict__ wt,
             _Float16* __restrict__ pooled2h, float* __restrict__ vldw)
{
  __shared__ _Float16 ldsw[32768];          // L3 fragment pool only (64 KB)
  __shared__ _Float16 ldsp[16][HH];         // pooled2 staging (4 KB)

  const int tid  = threadIdx.x;
  const int lane = tid & 63;
  const int w    = tid >> 6;                // 0..7
  const int l15  = lane & 15;
  const int lg   = lane >> 4;
  const int pidA = blockIdx.x * 16 + 2 * w;
  const int pidB = pidA + 1;

  // ---- stage L3 weights (coalesced uint4 copy), one barrier ----
  {
    const uint4* src = (const uint4*)(wt + 20480);
    uint4* dst = (uint4*)ldsw;
    for (int i = tid; i < 4096; i += 512) dst[i] = src[i];
  }

  // ---- masks: lanes 0-19 load A's, lanes 32-51 load B's ----
  int mrow = 0;
  if (lane < PP)                 mrow = maskp[(size_t)pidA * PP + lane];
  else if (lane >= 32 && lane < 32 + PP) mrow = maskp[(size_t)pidB * PP + (lane - 32)];
  const float vldA = (__ballot(lane < PP && mrow != 0) != 0ULL) ? 1.f : 0.f;
  const float vldB = (__ballot(lane >= 32 && mrow != 0) != 0ULL) ? 1.f : 0.f;
  const int mi0 = __shfl(mrow, l15, 64);            // A mask[l15]
  const int mi1 = __shfl(mrow, 32 + l15, 64);       // B mask[l15]
  const int mi2 = __shfl(mrow, (l15 < 4) ? (16 + l15) : (44 + l15), 64); // tail
  f32x4 mfv[3];
  mfv[0] = splat4((mi0 != 0) ? 1.f : 0.f);
  mfv[1] = splat4((mi1 != 0) ? 1.f : 0.f);
  mfv[2] = splat4((l15 < 8 && mi2 != 0) ? 1.f : 0.f);
  const f32x4 selA = splat4((l15 < 4) ? 1.f : 0.f);
  const f32x4 selB = splat4((l15 >= 4 && l15 < 8) ? 1.f : 0.f);

  // ---- X -> B-frags for 3 tiles (K=32: 13 real, rest 0) ----
  const float* xp = poly + (size_t)pidA * (PP * 13);
  const float* xq = poly + (size_t)pidB * (PP * 13);
  f16x8 x0, x1, x2;
#pragma unroll
  for (int jj = 0; jj < 4; jj++) {
    const int k = 4 * lg + jj;
    float v0 = 0.f, v1 = 0.f, v2 = 0.f;
    if (k < 13) {
      v0 = xp[l15 * 13 + k];
      v1 = xq[l15 * 13 + k];
      if (l15 < 4)      v2 = xp[(16 + l15) * 13 + k];
      else if (l15 < 8) v2 = xq[(12 + l15) * 13 + k];
    }
    x0[jj] = (_Float16)v0;  x0[4 + jj] = (_Float16)0.f;
    x1[jj] = (_Float16)v1;  x1[4 + jj] = (_Float16)0.f;
    x2[jj] = (_Float16)v2;  x2[4 + jj] = (_Float16)0.f;
  }

  __syncthreads();   // L3 staged

  const _Float16* wtL1 = wt;                // global (L2-resident)
  const _Float16* wtL2 = wt + 4096;         // global
  const _Float16* wtL3 = ldsw;              // LDS
  const _Float16* wtL4 = wt + 53248;        // global

  f32x4 acc[8][3];
  f16x8 Hf0[4], Hf1[4], Hf2[4];
  f32x4 pmA[8], pmB[8];

  // ---- L1: K=32 ----
  zero_acc3(acc);
  gemm3<1>(wtL1, 0, x0, x1, x2, acc, lane);
  ln3<false>(acc, b1, g1, be1, mfv, pmA, pmB, selA, selB, lg);
#pragma unroll
  for (int ks = 0; ks < 4; ks++) {
    Hf0[ks] = pack8(acc[2 * ks][0], acc[2 * ks + 1][0]);
    Hf1[ks] = pack8(acc[2 * ks][1], acc[2 * ks + 1][1]);
    Hf2[ks] = pack8(acc[2 * ks][2], acc[2 * ks + 1][2]);
  }

  // ---- L2: K=128, mask+pool ----
  zero_acc3(acc);
#pragma unroll
  for (int ks = 0; ks < 4; ks++) gemm3<4>(wtL2, ks, Hf0[ks], Hf1[ks], Hf2[ks], acc, lane);
#pragma unroll
  for (int nt = 0; nt < 8; nt++) { pmA[nt] = splat4(0.f); pmB[nt] = splat4(0.f); }
  ln3<true>(acc, b2, g2, be2, mfv, pmA, pmB, selA, selB, lg);
#pragma unroll
  for (int nt = 0; nt < 8; nt++)
#pragma unroll
    for (int j = 0; j < 4; j++) {
      float p = pmA[nt][j];
      p = fmaxf(p, __shfl_xor(p, 1, 64));
      p = fmaxf(p, __shfl_xor(p, 2, 64));
      p = fmaxf(p, __shfl_xor(p, 4, 64));
      p = fmaxf(p, __shfl_xor(p, 8, 64));
      pmA[nt][j] = p;
      float q = pmB[nt][j];
      q = fmaxf(q, __shfl_xor(q, 1, 64));
      q = fmaxf(q, __shfl_xor(q, 2, 64));
      q = fmaxf(q, __shfl_xor(q, 4, 64));
      q = fmaxf(q, __shfl_xor(q, 8, 64));
      pmB[nt][j] = q;
    }
  f16x8 PfA[4], PfB[4], Pf2[4];
#pragma unroll
  for (int ks = 0; ks < 4; ks++) {
    PfA[ks] = pack8(pmA[2 * ks], pmA[2 * ks + 1]);
    PfB[ks] = pack8(pmB[2 * ks], pmB[2 * ks + 1]);
    Pf2[ks] = sel8(l15 < 4, PfA[ks], PfB[ks]);
  }
#pragma unroll
  for (int ks = 0; ks < 4; ks++) {
    Hf0[ks] = pack8(acc[2 * ks][0], acc[2 * ks + 1][0]);
    Hf1[ks] = pack8(acc[2 * ks][1], acc[2 * ks + 1][1]);
    Hf2[ks] = pack8(acc[2 * ks][2], acc[2 * ks + 1][2]);
  }

  // ---- L3: K=256 = feat (ks 0-3) + pooled (ks 4-7), LDS frags ----
  zero_acc3(acc);
#pragma unroll
  for (int ks = 0; ks < 4; ks++) gemm3<8>(wtL3, ks, Hf0[ks], Hf1[ks], Hf2[ks], acc, lane);
#pragma unroll
  for (int ks = 4; ks < 8; ks++) gemm3<8>(wtL3, ks, PfA[ks - 4], PfB[ks - 4], Pf2[ks - 4], acc, lane);
  ln3<false>(acc, f2b1, f2g1, f2be1, mfv, pmA, pmB, selA, selB, lg);
#pragma unroll
  for (int ks = 0; ks < 4; ks++) {
    Hf0[ks] = pack8(acc[2 * ks][0], acc[2 * ks + 1][0]);
    Hf1[ks] = pack8(acc[2 * ks][1], acc[2 * ks + 1][1]);
    Hf2[ks] = pack8(acc[2 * ks][2], acc[2 * ks + 1][2]);
  }

  // ---- L4: K=128, mask+pool -> pooled2 ----
  zero_acc3(acc);
#pragma unroll
  for (int ks = 0; ks < 4; ks++) gemm3<4>(wtL4, ks, Hf0[ks], Hf1[ks], Hf2[ks], acc, lane);
#pragma unroll
  for (int nt = 0; nt < 8; nt++) { pmA[nt] = splat4(0.f); pmB[nt] = splat4(0.f); }
  ln3<true>(acc, f2b2, f2g2, f2be2, mfv, pmA, pmB, selA, selB, lg);
#pragma unroll
  for (int nt = 0; nt < 8; nt++)
#pragma unroll
    for (int j = 0; j < 4; j++) {
      float p = pmA[nt][j];
      p = fmaxf(p, __shfl_xor(p, 1, 64));
      p = fmaxf(p, __shfl_xor(p, 2, 64));
      p = fmaxf(p, __shfl_xor(p, 4, 64));
      p = fmaxf(p, __shfl_xor(p, 8, 64));
      pmA[nt][j] = p;
      float q = pmB[nt][j];
      q = fmaxf(q, __shfl_xor(q, 1, 64));
      q = fmaxf(q, __shfl_xor(q, 2, 64));
      q = fmaxf(q, __shfl_xor(q, 4, 64));
      q = fmaxf(q, __shfl_xor(q, 8, 64));
      pmB[nt][j] = q;
    }

  // ---- emit pooled2 (fp16) + vld; coalesced via per-wave LDS rows ----
  if (l15 == 0) {
#pragma unroll
    for (int nt = 0; nt < 8; nt++)
#pragma unroll
      for (int j = 0; j < 4; j++) {
        ldsp[2 * w][nt * 16 + 4 * lg + j]     = (_Float16)pmA[nt][j];
        ldsp[2 * w + 1][nt * 16 + 4 * lg + j] = (_Float16)pmB[nt][j];
      }
  }
  // same-wave LDS dependency (v7..v13-verified pattern, no barrier)
  const unsigned int pvA = *(const unsigned int*)(&ldsp[2 * w][lane * 2]);
  const unsigned int pvB = *(const unsigned int*)(&ldsp[2 * w + 1][lane * 2]);
  *(unsigned int*)(pooled2h + (size_t)pidA * HH + lane * 2) = pvA;
  *(unsigned int*)(pooled2h + (size_t)pidB * HH + lane * 2) = pvB;
  if (lane == 0) { vldw[pidA] = vldA; vldw[pidB] = vldB; }
}

// ---- k_head (R6/R8/R10/R13-verified) ----
extern "C" __global__ void __launch_bounds__(256, 2)
k_head(const _Float16* __restrict__ pooled2h, const float* __restrict__ vldw,
       const _Float16* __restrict__ wt,
       const float* __restrict__ fob1, const float* __restrict__ fob2,
       float* __restrict__ out)
{
  __shared__ _Float16 Z1[64 * PSTR];
  const int tid = threadIdx.x, lane = tid & 63, w = tid >> 6;
  const int l15 = lane & 15, lg = lane >> 4;
  const int rbase = blockIdx.x * 64;

  const _Float16* FOW1t = wt + 69632;
  const _Float16* FOW2t = wt + 86016;

  {
    f32x4 az[4][2];
    const float bz0 = fob1[32 * w + l15];
    const float bz1 = fob1[32 * w + 16 + l15];
#pragma unroll
    for (int mt = 0; mt < 4; mt++) { az[mt][0] = splat4(bz0); az[mt][1] = splat4(bz1); }
    f16x8 bfr[2][4];
#pragma unroll
    for (int nt = 0; nt < 2; nt++) {
      const _Float16* bp = FOW1t + (size_t)((2 * w + nt) * 16 + l15) * 128 + 4 * lg;
#pragma unroll
      for (int ks = 0; ks < 4; ks++) bfr[nt][ks] = ldfrag2(bp + 32 * ks);
    }
#pragma unroll
    for (int mt = 0; mt < 4; mt++) {
      const _Float16* ap = pooled2h + (size_t)(rbase + mt * 16 + l15) * HH + 4 * lg;
#pragma unroll
      for (int ks = 0; ks < 4; ks++) {
        f16x8 a = ldfrag2(ap + 32 * ks);
        az[mt][0] = MFMA(a, bfr[0][ks], az[mt][0]);
        az[mt][1] = MFMA(a, bfr[1][ks], az[mt][1]);
      }
    }
#pragma unroll
    for (int mt = 0; mt < 4; mt++)
#pragma unroll
      for (int j = 0; j < 4; j++) {
        const int row = mt * 16 + lg * 4 + j;
        Z1[row * PSTR + 32 * w + l15]      = (_Float16)fmaxf(az[mt][0][j], 0.f);
        Z1[row * PSTR + 32 * w + 16 + l15] = (_Float16)fmaxf(az[mt][1][j], 0.f);
      }
  }
  __syncthreads();

  {
    f16x8 a[4][4];
#pragma unroll
    for (int mt = 0; mt < 4; mt++)
#pragma unroll
      for (int ks = 0; ks < 4; ks++)
        a[mt][ks] = ldfrag2(Z1 + (mt * 16 + l15) * PSTR + 4 * lg + 32 * ks);
    f32x4 o[4][4];
#pragma unroll
    for (int nt = 0; nt < 4; nt++) {
      const int c = (4 * w + nt) * 16 + l15;
      const float bo = fob2[c];
#pragma unroll
      for (int mt = 0; mt < 4; mt++) o[mt][nt] = splat4(bo);
      const _Float16* bp = FOW2t + (size_t)((4 * w + nt) * 16 + l15) * 128 + 4 * lg;
#pragma unroll
      for (int ks = 0; ks < 4; ks++) {
        f16x8 b = ldfrag2(bp + 32 * ks);
#pragma unroll
        for (int mt = 0; mt < 4; mt++) o[mt][nt] = MFMA(a[mt][ks], b, o[mt][nt]);
      }
    }
#pragma unroll
    for (int mt = 0; mt < 4; mt++)
#pragma unroll
      for (int j = 0; j < 4; j++) {
        const int row = mt * 16 + lg * 4 + j;
        const float v = vldw[rbase + row];
#pragma unroll
        for (int nt = 0; nt < 4; nt++)
          out[(size_t)(rbase + row) * OO + (4 * w + nt) * 16 + l15] = o[mt][nt][j] * v;
      }
  }
}

extern "C" void kernel_launch(void* const* d_in, const int* in_sizes, int n_in,
                              void* d_out, int out_size, void* d_ws, size_t ws_size,
                              hipStream_t stream)
{
  const float* poly  = (const float*)d_in[0];
  const int*   mask  = (const int*)d_in[1];
  const float* W1    = (const float*)d_in[2];
  const float* b1    = (const float*)d_in[3];
  const float* g1    = (const float*)d_in[4];
  const float* be1   = (const float*)d_in[5];
  const float* W2    = (const float*)d_in[6];
  const float* b2    = (const float*)d_in[7];
  const float* g2    = (const float*)d_in[8];
  const float* be2   = (const float*)d_in[9];
  const float* f2W1  = (const float*)d_in[10];
  const float* f2b1  = (const float*)d_in[11];
  const float* f2g1  = (const float*)d_in[12];
  const float* f2be1 = (const float*)d_in[13];
  const float* f2W2  = (const float*)d_in[14];
  const float* f2b2  = (const float*)d_in[15];
  const float* f2g2  = (const float*)d_in[16];
  const float* f2be2 = (const float*)d_in[17];
  const float* foW1  = (const float*)d_in[18];
  const float* fob1  = (const float*)d_in[19];
  const float* foW2  = (const float*)d_in[20];
  const float* fob2  = (const float*)d_in[21];
  float* out = (float*)d_out;

  const int npoly = in_sizes[0] / (PP * 13);   // 16384

  // ws layout: wt fp16 118784 halves (237,568 B) | pooled2h fp16 npoly*128 | vldw f32 npoly
  char* ws = (char*)d_ws;
  _Float16* wt       = (_Float16*)ws;
  _Float16* pooled2h = (_Float16*)(ws + 237568);
  float*    vldw     = (float*)(ws + 237568 + (size_t)npoly * HH * 2);

  prep_weights<<<dim3((118784 + 255) / 256), dim3(256), 0, stream>>>(
      W1, W2, f2W1, f2W2, foW1, foW2, wt);

  polynet_main<<<dim3(npoly / 16), dim3(512), 0, stream>>>(
      poly, mask, b1, g1, be1, b2, g2, be2,
      f2b1, f2g1, f2be1, f2b2, f2g2, f2be2,
      wt, pooled2h, vldw);

  k_head<<<dim3(npoly / 64), dim3(256), 0, stream>>>(
      pooled2h, vldw, wt, fob1, fob2, out);
}

// Round 18
// 148.080 us; speedup vs baseline: 2.3021x; 1.1366x over previous
//
#include <hip/hip_runtime.h>
#include <math.h>

// PolylineNet v18 == v13 (best verified: 148us, R13). Restored after the
// occupancy-ladder exploration (R14-R17) proved v13 sits at its structural
// cap: unified VGPR+AGPR file = 64+64 = 128 regs/wave -> 16 waves/CU max;
// accumulator tile (64 AGPR) is irreducible (LN needs all 128 channels live).
// Structure: 16 waves/block (1 polyline/wave), 136KB LDS weight pool,
// 1 barrier, DPP max-pool on VALU, packed-math LN, k_head fission.

#define PP 20
#define HH 128
#define OO 256
#define NW 16          // waves (=polylines) per block
#define PSTR 136       // k_head LDS stride

typedef __fp16   fp16x2 __attribute__((ext_vector_type(2)));   // cvt_pkrtz return type
typedef _Float16 f16x4 __attribute__((ext_vector_type(4)));
typedef _Float16 f16x8 __attribute__((ext_vector_type(8)));
typedef float    f32x4 __attribute__((ext_vector_type(4)));

__device__ __forceinline__ f32x4 splat4(float x) { f32x4 v = {x, x, x, x}; return v; }

__device__ __forceinline__ f32x4 max4(f32x4 a, f32x4 b)
{
#if __has_builtin(__builtin_elementwise_max)
  return __builtin_elementwise_max(a, b);
#else
  f32x4 r;
  r[0] = fmaxf(a[0], b[0]); r[1] = fmaxf(a[1], b[1]);
  r[2] = fmaxf(a[2], b[2]); r[3] = fmaxf(a[3], b[3]);
  return r;
#endif
}

__device__ __forceinline__ f32x4 MFMA(f16x8 a, f16x8 b, f32x4 c)
{
  return __builtin_amdgcn_mfma_f32_16x16x32_f16(a, b, c, 0, 0, 0);
}

// R6-style fragment load for k_head ([N][K] row-major weights / dense rows).
__device__ __forceinline__ f16x8 ldfrag2(const _Float16* p)
{
  f16x8 r;
  f16x4* r4 = reinterpret_cast<f16x4*>(&r);
  r4[0] = *reinterpret_cast<const f16x4*>(p);
  r4[1] = *reinterpret_cast<const f16x4*>(p + 16);
  return r;
}

// Pack two f32x4 channel groups into one B-operand f16x8 via v_cvt_pkrtz.
__device__ __forceinline__ f16x8 pack8(const f32x4 a, const f32x4 b)
{
  union { fp16x2 h2[4]; f16x8 h8; } u;
  u.h2[0] = __builtin_amdgcn_cvt_pkrtz(a[0], a[1]);
  u.h2[1] = __builtin_amdgcn_cvt_pkrtz(a[2], a[3]);
  u.h2[2] = __builtin_amdgcn_cvt_pkrtz(b[0], b[1]);
  u.h2[3] = __builtin_amdgcn_cvt_pkrtz(b[2], b[3]);
  return u.h8;
}

// ---- DPP pool reduction helpers (VALU, no LDS port) ----
template<int CTRL>
__device__ __forceinline__ unsigned mov_dpp_u32(unsigned v)
{
  return (unsigned)__builtin_amdgcn_update_dpp(0, (int)v, CTRL, 0xF, 0xF, true);
}

// packed fp16 max (values are finite, post-ReLU >= 0)
__device__ __forceinline__ unsigned hmax2_u32(unsigned a, unsigned b)
{
  union { unsigned u; _Float16 h[2]; } ua, ub, ur;
  ua.u = a; ub.u = b;
  ur.h[0] = (ua.h[0] > ub.h[0]) ? ua.h[0] : ub.h[0];
  ur.h[1] = (ua.h[1] > ub.h[1]) ? ua.h[1] : ub.h[1];
  return ur.u;
}

// max-reduce over the 16 lanes of each DPP row (the l15 / points axis):
// row_ror:1,2,4,8 -> every lane ends with the row max.
__device__ __forceinline__ unsigned pool_reduce16(unsigned v)
{
  v = hmax2_u32(v, mov_dpp_u32<0x121>(v));   // ror:1
  v = hmax2_u32(v, mov_dpp_u32<0x122>(v));   // ror:2
  v = hmax2_u32(v, mov_dpp_u32<0x124>(v));   // ror:4
  v = hmax2_u32(v, mov_dpp_u32<0x128>(v));   // ror:8
  return v;
}

// One K-step over all 8 N-tiles, both M-tiles (v7/v8-verified; wbase in LDS).
template<int KSROW>
__device__ __forceinline__ void gemm_ks(const _Float16* wbase, int ks,
                                        const f16x8 bf0, const f16x8 bf1,
                                        f32x4 acc[8][2], int lane)
{
#pragma unroll
  for (int nt = 0; nt < 8; nt++) {
    const f16x8 wf = *(const f16x8*)(wbase + (size_t)(nt * KSROW + ks) * 512 + lane * 8);
    acc[nt][0] = MFMA(wf, bf0, acc[nt][0]);
    acc[nt][1] = MFMA(wf, bf1, acc[nt][1]);
  }
}

__device__ __forceinline__ void zero_acc(f32x4 acc[8][2])
{
#pragma unroll
  for (int nt = 0; nt < 8; nt++) { acc[nt][0] = splat4(0.f); acc[nt][1] = splat4(0.f); }
}

// LayerNorm over channels, fully vectorized (v9b-verified).
template<bool DOMASKPOOL>
__device__ __forceinline__ void ln_blk(f32x4 acc[8][2],
                                       const float* __restrict__ bv,
                                       const float* __restrict__ gv,
                                       const float* __restrict__ bev,
                                       float mf0, float mf1,
                                       f32x4 pm[8], int lg)
{
  // bias add + moments
  f32x4 sv0 = splat4(0.f), sv1 = splat4(0.f), qv0 = splat4(0.f), qv1 = splat4(0.f);
#pragma unroll
  for (int nt = 0; nt < 8; nt++) {
    const f32x4 bb = *(const f32x4*)(bv + 16 * nt + 4 * lg);
    f32x4 v0 = acc[nt][0] + bb;
    f32x4 v1 = acc[nt][1] + bb;
    acc[nt][0] = v0;  acc[nt][1] = v1;
    sv0 += v0;  qv0 = v0 * v0 + qv0;
    sv1 += v1;  qv1 = v1 * v1 + qv1;
  }
  float mu[2], rs[2];
#pragma unroll
  for (int mt = 0; mt < 2; mt++) {
    const f32x4 sv = mt ? sv1 : sv0;
    const f32x4 qv = mt ? qv1 : qv0;
    float s = (sv[0] + sv[1]) + (sv[2] + sv[3]);
    float q = (qv[0] + qv[1]) + (qv[2] + qv[3]);
    s += __shfl_xor(s, 16, 64); s += __shfl_xor(s, 32, 64);
    q += __shfl_xor(q, 16, 64); q += __shfl_xor(q, 32, 64);
    mu[mt] = s * (1.f / 128.f);
    rs[mt] = rsqrtf(fmaxf(q * (1.f / 128.f) - mu[mt] * mu[mt], 0.f) + 1e-5f);
  }
  // normalize: v = fma(fma(acc, rs, -mu*rs), g, be); relu; mask; pool
  const f32x4 z4 = splat4(0.f);
  const f32x4 rs0 = splat4(rs[0]),           rs1 = splat4(rs[1]);
  const f32x4 nm0 = splat4(-mu[0] * rs[0]),  nm1 = splat4(-mu[1] * rs[1]);
  const f32x4 m0  = splat4(mf0),             m1  = splat4(mf1);
#pragma unroll
  for (int nt = 0; nt < 8; nt++) {
    const f32x4 g4  = *(const f32x4*)(gv  + 16 * nt + 4 * lg);
    const f32x4 be4 = *(const f32x4*)(bev + 16 * nt + 4 * lg);
    f32x4 t0 = acc[nt][0] * rs0 + nm0;
    f32x4 t1 = acc[nt][1] * rs1 + nm1;
    f32x4 v0 = max4(t0 * g4 + be4, z4);
    f32x4 v1 = max4(t1 * g4 + be4, z4);
    if (DOMASKPOOL) {
      v0 = v0 * m0;
      v1 = v1 * m1;
      pm[nt] = max4(pm[nt], max4(v0, v1));
    }
    acc[nt][0] = v0;  acc[nt][1] = v1;
  }
}

// pack pm[8] (f32x4, per-lane partial maxima) to 16 packed-fp16 u32 and
// DPP-reduce each over the 16-lane row -> pp[i] holds the polyline max.
__device__ __forceinline__ void pool_pack_reduce(const f32x4 pm[8], unsigned pp[16])
{
#pragma unroll
  for (int nt = 0; nt < 8; nt++) {
    union { fp16x2 h; unsigned u; } a, b;
    a.h = __builtin_amdgcn_cvt_pkrtz(pm[nt][0], pm[nt][1]);
    b.h = __builtin_amdgcn_cvt_pkrtz(pm[nt][2], pm[nt][3]);
    pp[2 * nt]     = pool_reduce16(a.u);
    pp[2 * nt + 1] = pool_reduce16(b.u);
  }
}

// ---- prep: L1-L4 fragment-linear (v7-verified) + FOW1/FOW2 [N][K] (R6-verified) ----
__global__ void prep_weights(const float* __restrict__ W1, const float* __restrict__ W2,
                             const float* __restrict__ F2W1, const float* __restrict__ F2W2,
                             const float* __restrict__ FO1, const float* __restrict__ FO2,
                             _Float16* __restrict__ wt)
{
  const int idx = blockIdx.x * 256 + threadIdx.x;
  if (idx >= 118784) return;
  float v;
  if (idx < 69632) {
    const int jj = idx & 7;
    const int lane = (idx >> 3) & 63;
    const int fg = idx >> 9;
    const int l15 = lane & 15, lg = lane >> 4;
    const int kin = 4 * lg + (jj & 3) + ((jj & 4) << 2);
    if (fg < 8)        { const int n = fg * 16 + l15;                  v = (kin < 13) ? W1[kin * 128 + n] : 0.f; }
    else if (fg < 40)  { const int f = fg - 8;   const int n = (f >> 2) * 16 + l15, k = (f & 3) * 32 + kin; v = W2[k * 128 + n]; }
    else if (fg < 104) { const int f = fg - 40;  const int n = (f >> 3) * 16 + l15, k = (f & 7) * 32 + kin; v = F2W1[k * 128 + n]; }
    else               { const int f = fg - 104; const int n = (f >> 2) * 16 + l15, k = (f & 3) * 32 + kin; v = F2W2[k * 128 + n]; }
  } else if (idx < 86016) { const int j = idx - 69632; const int n = j >> 7, k = j & 127; v = FO1[k * 128 + n]; }
  else                    { const int j = idx - 86016; const int n = j >> 7, k = j & 127; v = FO2[k * 256 + n]; }
  wt[idx] = (_Float16)v;
}

// ---- main kernel: 16 waves, LDS-shared weights, 1 barrier (v13-verified) ----
extern "C" __global__ void __launch_bounds__(1024, 1)
polynet_main(const float* __restrict__ poly, const int* __restrict__ maskp,
             const float* __restrict__ b1,  const float* __restrict__ g1,  const float* __restrict__ be1,
             const float* __restrict__ b2,  const float* __restrict__ g2,  const float* __restrict__ be2,
             const float* __restrict__ f2b1, const float* __restrict__ f2g1, const float* __restrict__ f2be1,
             const float* __restrict__ f2b2, const float* __restrict__ f2g2, const float* __restrict__ f2be2,
             const _Float16* __restrict__ wt,
             _Float16* __restrict__ pooled2h, float* __restrict__ vldw)
{
  __shared__ _Float16 ldsw[69632];          // L1-L4 fragment pool (136 KB)
  __shared__ _Float16 ldsp[NW][HH];         // pooled2 staging (4 KB)

  const int tid  = threadIdx.x;
  const int lane = tid & 63;
  const int w    = tid >> 6;
  const int l15  = lane & 15;
  const int lg   = lane >> 4;
  const int pid  = blockIdx.x * NW + w;

  // ---- stage weights (coalesced uint4 copy), one barrier ----
  {
    const uint4* src = (const uint4*)wt;
    uint4* dst = (uint4*)ldsw;
    for (int i = tid; i < 8704; i += 1024) dst[i] = src[i];
  }

  // ---- mask (in-wave) ----
  int mrow = 0;
  if (lane < PP) mrow = maskp[(size_t)pid * PP + lane];
  const float vld = (__ballot(mrow != 0) != 0ULL) ? 1.f : 0.f;
  const int mi0 = __shfl(mrow, l15, 64);
  const int mi1 = __shfl(mrow, 16 + l15, 64);
  const float mf0 = (mi0 != 0) ? 1.f : 0.f;
  const float mf1 = (l15 < 4 && mi1 != 0) ? 1.f : 0.f;

  // ---- X -> B-frags ----
  const float* xp = poly + (size_t)pid * (PP * 13);
  f16x8 x0, x1;
#pragma unroll
  for (int jj = 0; jj < 4; jj++) {
    const int k = 4 * lg + jj;
    const float v0 = (k < 13) ? xp[l15 * 13 + k] : 0.f;
    const float v1 = (k < 13 && l15 < 4) ? xp[(16 + l15) * 13 + k] : 0.f;
    x0[jj] = (_Float16)v0;  x0[4 + jj] = (_Float16)0.f;
    x1[jj] = (_Float16)v1;  x1[4 + jj] = (_Float16)0.f;
  }

  __syncthreads();   // weights staged

  const _Float16* wtL1 = ldsw;
  const _Float16* wtL2 = ldsw + 4096;
  const _Float16* wtL3 = ldsw + 20480;
  const _Float16* wtL4 = ldsw + 53248;

  f32x4 acc[8][2];
  f16x8 Hf0[4], Hf1[4];
  f32x4 pm[8];
  unsigned pp[16];

  // ---- L1: K=32 ----
  zero_acc(acc);
  gemm_ks<1>(wtL1, 0, x0, x1, acc, lane);
  ln_blk<false>(acc, b1, g1, be1, mf0, mf1, pm, lg);
#pragma unroll
  for (int ks = 0; ks < 4; ks++) {
    Hf0[ks] = pack8(acc[2 * ks][0], acc[2 * ks + 1][0]);
    Hf1[ks] = pack8(acc[2 * ks][1], acc[2 * ks + 1][1]);
  }

  // ---- L2: K=128, mask+pool ----
  zero_acc(acc);
#pragma unroll
  for (int ks = 0; ks < 4; ks++) gemm_ks<4>(wtL2, ks, Hf0[ks], Hf1[ks], acc, lane);
#pragma unroll
  for (int nt = 0; nt < 8; nt++) pm[nt] = splat4(0.f);
  ln_blk<true>(acc, b2, g2, be2, mf0, mf1, pm, lg);
  pool_pack_reduce(pm, pp);                   // DPP reduce (VALU)
  f16x8 Pf[4];
#pragma unroll
  for (int ks = 0; ks < 4; ks++) {
    union { unsigned u[4]; f16x8 h; } c;
    c.u[0] = pp[4 * ks];     c.u[1] = pp[4 * ks + 1];
    c.u[2] = pp[4 * ks + 2]; c.u[3] = pp[4 * ks + 3];
    Pf[ks] = c.h;
  }
#pragma unroll
  for (int ks = 0; ks < 4; ks++) {
    Hf0[ks] = pack8(acc[2 * ks][0], acc[2 * ks + 1][0]);
    Hf1[ks] = pack8(acc[2 * ks][1], acc[2 * ks + 1][1]);
  }

  // ---- L3: K=256 = feat + pooled ----
  zero_acc(acc);
#pragma unroll
  for (int ks = 0; ks < 4; ks++) gemm_ks<8>(wtL3, ks, Hf0[ks], Hf1[ks], acc, lane);
#pragma unroll
  for (int ks = 4; ks < 8; ks++) gemm_ks<8>(wtL3, ks, Pf[ks - 4], Pf[ks - 4], acc, lane);
  ln_blk<false>(acc, f2b1, f2g1, f2be1, mf0, mf1, pm, lg);
#pragma unroll
  for (int ks = 0; ks < 4; ks++) {
    Hf0[ks] = pack8(acc[2 * ks][0], acc[2 * ks + 1][0]);
    Hf1[ks] = pack8(acc[2 * ks][1], acc[2 * ks + 1][1]);
  }

  // ---- L4: K=128, mask+pool -> pooled2 ----
  zero_acc(acc);
#pragma unroll
  for (int ks = 0; ks < 4; ks++) gemm_ks<4>(wtL4, ks, Hf0[ks], Hf1[ks], acc, lane);
#pragma unroll
  for (int nt = 0; nt < 8; nt++) pm[nt] = splat4(0.f);
  ln_blk<true>(acc, f2b2, f2g2, f2be2, mf0, mf1, pm, lg);
  pool_pack_reduce(pm, pp);                   // DPP reduce (VALU)

  // ---- emit pooled2 (packed fp16 u32) + vld; coalesced via per-wave LDS row ----
  if (l15 == 0) {
    unsigned* lp = (unsigned*)&ldsp[w][0];    // 64 u32 per row
#pragma unroll
    for (int nt = 0; nt < 8; nt++) {
      lp[8 * nt + 2 * lg]     = pp[2 * nt];       // channels 16nt+4lg+{0,1}
      lp[8 * nt + 2 * lg + 1] = pp[2 * nt + 1];   // channels 16nt+4lg+{2,3}
    }
  }
  // same-wave LDS dependency (v7/v8/v9b-verified pattern, no barrier)
  const unsigned int pv = *(const unsigned int*)(&ldsp[w][lane * 2]);
  *(unsigned int*)(pooled2h + (size_t)pid * HH + lane * 2) = pv;
  if (lane == 0) vldw[pid] = vld;
}

// ---- k_head (R6/R8/R10/R13-verified) ----
extern "C" __global__ void __launch_bounds__(256, 2)
k_head(const _Float16* __restrict__ pooled2h, const float* __restrict__ vldw,
       const _Float16* __restrict__ wt,
       const float* __restrict__ fob1, const float* __restrict__ fob2,
       float* __restrict__ out)
{
  __shared__ _Float16 Z1[64 * PSTR];
  const int tid = threadIdx.x, lane = tid & 63, w = tid >> 6;
  const int l15 = lane & 15, lg = lane >> 4;
  const int rbase = blockIdx.x * 64;

  const _Float16* FOW1t = wt + 69632;
  const _Float16* FOW2t = wt + 86016;

  {
    f32x4 az[4][2];
    const float bz0 = fob1[32 * w + l15];
    const float bz1 = fob1[32 * w + 16 + l15];
#pragma unroll
    for (int mt = 0; mt < 4; mt++) { az[mt][0] = splat4(bz0); az[mt][1] = splat4(bz1); }
    f16x8 bfr[2][4];
#pragma unroll
    for (int nt = 0; nt < 2; nt++) {
      const _Float16* bp = FOW1t + (size_t)((2 * w + nt) * 16 + l15) * 128 + 4 * lg;
#pragma unroll
      for (int ks = 0; ks < 4; ks++) bfr[nt][ks] = ldfrag2(bp + 32 * ks);
    }
#pragma unroll
    for (int mt = 0; mt < 4; mt++) {
      const _Float16* ap = pooled2h + (size_t)(rbase + mt * 16 + l15) * HH + 4 * lg;
#pragma unroll
      for (int ks = 0; ks < 4; ks++) {
        f16x8 a = ldfrag2(ap + 32 * ks);
        az[mt][0] = MFMA(a, bfr[0][ks], az[mt][0]);
        az[mt][1] = MFMA(a, bfr[1][ks], az[mt][1]);
      }
    }
#pragma unroll
    for (int mt = 0; mt < 4; mt++)
#pragma unroll
      for (int j = 0; j < 4; j++) {
        const int row = mt * 16 + lg * 4 + j;
        Z1[row * PSTR + 32 * w + l15]      = (_Float16)fmaxf(az[mt][0][j], 0.f);
        Z1[row * PSTR + 32 * w + 16 + l15] = (_Float16)fmaxf(az[mt][1][j], 0.f);
      }
  }
  __syncthreads();

  {
    f16x8 a[4][4];
#pragma unroll
    for (int mt = 0; mt < 4; mt++)
#pragma unroll
      for (int ks = 0; ks < 4; ks++)
        a[mt][ks] = ldfrag2(Z1 + (mt * 16 + l15) * PSTR + 4 * lg + 32 * ks);
    f32x4 o[4][4];
#pragma unroll
    for (int nt = 0; nt < 4; nt++) {
      const int c = (4 * w + nt) * 16 + l15;
      const float bo = fob2[c];
#pragma unroll
      for (int mt = 0; mt < 4; mt++) o[mt][nt] = splat4(bo);
      const _Float16* bp = FOW2t + (size_t)((4 * w + nt) * 16 + l15) * 128 + 4 * lg;
#pragma unroll
      for (int ks = 0; ks < 4; ks++) {
        f16x8 b = ldfrag2(bp + 32 * ks);
#pragma unroll
        for (int mt = 0; mt < 4; mt++) o[mt][nt] = MFMA(a[mt][ks], b, o[mt][nt]);
      }
    }
#pragma unroll
    for (int mt = 0; mt < 4; mt++)
#pragma unroll
      for (int j = 0; j < 4; j++) {
        const int row = mt * 16 + lg * 4 + j;
        const float v = vldw[rbase + row];
#pragma unroll
        for (int nt = 0; nt < 4; nt++)
          out[(size_t)(rbase + row) * OO + (4 * w + nt) * 16 + l15] = o[mt][nt][j] * v;
      }
  }
}

extern "C" void kernel_launch(void* const* d_in, const int* in_sizes, int n_in,
                              void* d_out, int out_size, void* d_ws, size_t ws_size,
                              hipStream_t stream)
{
  const float* poly  = (const float*)d_in[0];
  const int*   mask  = (const int*)d_in[1];
  const float* W1    = (const float*)d_in[2];
  const float* b1    = (const float*)d_in[3];
  const float* g1    = (const float*)d_in[4];
  const float* be1   = (const float*)d_in[5];
  const float* W2    = (const float*)d_in[6];
  const float* b2    = (const float*)d_in[7];
  const float* g2    = (const float*)d_in[8];
  const float* be2   = (const float*)d_in[9];
  const float* f2W1  = (const float*)d_in[10];
  const float* f2b1  = (const float*)d_in[11];
  const float* f2g1  = (const float*)d_in[12];
  const float* f2be1 = (const float*)d_in[13];
  const float* f2W2  = (const float*)d_in[14];
  const float* f2b2  = (const float*)d_in[15];
  const float* f2g2  = (const float*)d_in[16];
  const float* f2be2 = (const float*)d_in[17];
  const float* foW1  = (const float*)d_in[18];
  const float* fob1  = (const float*)d_in[19];
  const float* foW2  = (const float*)d_in[20];
  const float* fob2  = (const float*)d_in[21];
  float* out = (float*)d_out;

  const int npoly = in_sizes[0] / (PP * 13);   // 16384

  // ws layout: wt fp16 118784 halves (237,568 B) | pooled2h fp16 npoly*128 | vldw f32 npoly
  char* ws = (char*)d_ws;
  _Float16* wt       = (_Float16*)ws;
  _Float16* pooled2h = (_Float16*)(ws + 237568);
  float*    vldw     = (float*)(ws + 237568 + (size_t)npoly * HH * 2);

  prep_weights<<<dim3((118784 + 255) / 256), dim3(256), 0, stream>>>(
      W1, W2, f2W1, f2W2, foW1, foW2, wt);

  polynet_main<<<dim3(npoly / NW), dim3(1024), 0, stream>>>(
      poly, mask, b1, g1, be1, b2, g2, be2,
      f2b1, f2g1, f2be1, f2b2, f2g2, f2be2,
      wt, pooled2h, vldw);

  k_head<<<dim3(npoly / 64), dim3(256), 0, stream>>>(
      pooled2h, vldw, wt, fob1, fob2, out);
}